// Round 8
// baseline (14470.039 us; speedup 1.0000x reference)
//
#include <hip/hip_runtime.h>

#define HIDDEN   2048
#define T_STEPS  8192
#define WASHOUT  200
#define NWG      64
#define NTHR     1024
#define NWAVE    (NTHR / 64)                 // 16 waves
#define ROWS_PER_WG   (HIDDEN / NWG)         // 32
#define ROWS_PER_WAVE (ROWS_PER_WG / NWAVE)  // 2
#define NCHUNK   16                          // 16 chunks of 128 state elements
#define NREPL    8                           // one mailbox replica per XCD
#define REPL     (2 * HIDDEN)                // ull elements per replica (32 KB)

// ws layout: NREPL replicas of {unsigned long long pairs[2][HIDDEN]}.
// Pair = {value:hi32, step:lo32}: one 8B unit carries payload+tag.
// 0xAA poison tags self-correct across graph replays (a slot's stale tag is
// overwritten thousands of steps before the want sequence reaches it).
//
// R21 (this round): 16 WAVES (NTHR 512->1024). R7 proved the serial tail
// between detect and publish is fully on the critical path (tail shave gave
// -13.5%). The remaining tail scales with rows-per-wave, so halve it:
// 2 rows/wave, chunks of 128. Per-thread: 64 FMAs (was 128), 16 ds_read_b64
// (was 32 b128), poll = ONE dwordx4/lane (was two). Weights 64 VGPR
// (was 128) -> fits the 128-reg cap a 1024-thr block imposes (~94 live).
// Readout moves to wave 8 (non-publishing) so publish waves 0-7 never
// carry shuffle+atomic work. 4 waves/SIMD also hides more latency in the
// staggered chunk-arrival window.
// Kept from R18-R20 (each isolated): per-XCD replicas (R5 win), sc1
// cacheable polls / NO nt anywhere (R2), per-wave full-line publish +
// permlane swaps + fast tanh (R7 win), VGPR-pinned weights (R1),
// two barriers (R4: flag pipeline regressed), poison self-init.

// DPP add: x + dpp_perm(x). All-VALU (no DS round trip).
#define DPP_ADD(x, ctrl) ((x) + __int_as_float(__builtin_amdgcn_update_dpp( \
    0, __float_as_int(x), ctrl, 0xF, 0xF, true)))

typedef unsigned uint4v __attribute__((ext_vector_type(4)));
typedef unsigned uint2v __attribute__((ext_vector_type(2)));

// 64-lane sum via permlane{16,32}_swap self-swap (both outputs summed ->
// direction-agnostic). R20-proven builtin form (R19's asm form coalesced
// the two same-value "+v" operands into one reg and corrupted sums).
#define PERMLANE_SUM_1632(h)                                         \
  {                                                                  \
    uint2v s16 = __builtin_amdgcn_permlane16_swap(                   \
        __float_as_uint(h), __float_as_uint(h), false, false);       \
    h = __uint_as_float(s16.x) + __uint_as_float(s16.y);             \
    uint2v s32 = __builtin_amdgcn_permlane32_swap(                   \
        __float_as_uint(h), __float_as_uint(h), false, false);       \
    h = __uint_as_float(s32.x) + __uint_as_float(s32.y);             \
  }

__global__ __launch_bounds__(NTHR, 1) void esn_main(
    const float* __restrict__ u,
    const float* __restrict__ w_in,
    const float* __restrict__ w_res,
    const float* __restrict__ w_out,
    float* __restrict__ out,
    unsigned long long* __restrict__ pairs,
    int nrepl)
{
  const int g  = blockIdx.x;    // 0..63, one WG per CU
  const int j  = threadIdx.x;   // 0..1023
  const int wv = j >> 6;        // 0..15
  const int l  = j & 63;

  // which XCD am I on? poll only that replica. Uniform per wave (SGPR).
  unsigned xcc;
  asm("s_getreg_b32 %0, hwreg(HW_REG_XCC_ID)" : "=s"(xcc));
  const unsigned ri = xcc & (unsigned)(nrepl - 1);   // nrepl is 1 or 8
  unsigned long long* __restrict__ myrep = pairs + (size_t)ri * REPL;

  __shared__ float x_s[2][HIDDEN];      // double-buffered staged state (16 KB)
  __shared__ float u_s[T_STEPS];        // 32 KB
  __shared__ float fresh[ROWS_PER_WG];  // this WG's newest 32 values

#pragma unroll
  for (int k = 0; k < T_STEPS / NTHR; ++k) u_s[j + NTHR * k] = u[j + NTHR * k];

  // wave wv owns rows r0..r0+1 and state chunk wv (elements wv*128..+127);
  // lane l owns cols {c*128 + 2l, +1} of each chunk c.
  const int r0 = g * ROWS_PER_WG + wv * ROWS_PER_WAVE;

  float wreg[ROWS_PER_WAVE][2 * NCHUNK];  // 64 VGPR-resident weights/thread
#pragma unroll
  for (int i = 0; i < ROWS_PER_WAVE; ++i) {
#pragma unroll
    for (int c = 0; c < NCHUNK; ++c) {
      const float2 a = *(const float2*)&w_res[(r0 + i) * HIDDEN + c * 128 + 2 * l];
      wreg[i][2 * c + 0] = a.x; wreg[i][2 * c + 1] = a.y;
    }
  }
  // pin weights in VGPRs; value becomes opaque -> no refetch, no remat
#pragma unroll
  for (int i = 0; i < ROWS_PER_WAVE; ++i)
#pragma unroll
    for (int k = 0; k < 2 * NCHUNK; ++k)
      asm volatile("" : "+v"(wreg[i][k]));

  const float winl = w_in[r0 + (l & 1)];                             // lanes 0..1
  const float wol  = (wv == 8 && l < 32) ? w_out[g * 32 + l] : 0.f;  // wave 8

  __syncthreads();  // u_s ready

  for (int t = 0; t < T_STEPS; ++t) {
    float d0 = 0.f, d1 = 0.f;
    const unsigned b = (unsigned)((t - 1) & 1);
    if (t > 0) {
      const unsigned want = (unsigned)(t - 1);
      // wave wv polls its 128-pair chunk of ITS XCD'S REPLICA:
      // ONE 16B sc1 load per lane per round (2 pairs).
      const unsigned long long* bp = myrep + b * HIDDEN + (wv << 7) + 2 * l;
      uint4v A;   // [tag0, val0, tag1, val1]
      for (;;) {
        asm volatile(
            "global_load_dwordx4 %0, %1, off sc1\n\t"
            "s_waitcnt vmcnt(0)"
            : "=&v"(A)
            : "v"(bp)
            : "memory");
        if ((A.x == want) & (A.z == want)) break;
      }
      float2 xv;
      xv.x = __uint_as_float(A.y);
      xv.y = __uint_as_float(A.w);
      *(float2*)&x_s[b][(wv << 7) + 2 * l] = xv;  // one ds_write_b64
    }
    __syncthreads();  // barrier 1: all chunks staged

    if (t > 0) {
#pragma unroll
      for (int c = 0; c < NCHUNK; ++c) {
        const float2 x2 = *(const float2*)&x_s[b][(c << 7) + 2 * l];
        d0 = fmaf(wreg[0][2 * c + 0], x2.x, d0);
        d0 = fmaf(wreg[0][2 * c + 1], x2.y, d0);
        d1 = fmaf(wreg[1][2 * c + 0], x2.x, d1);
        d1 = fmaf(wreg[1][2 * c + 1], x2.y, d1);
      }
    }

    // reduce: parity-preserving all-VALU chain. After xor1+select, even
    // lanes carry row0 partials, odd lanes row1; xor2/ror4/ror8/swap16/
    // swap32 all preserve lane parity -> lane 0 = row r0, lane 1 = r0+1.
    float e0 = DPP_ADD(d0, 0xB1);   // quad_perm [1,0,3,2]  (xor 1)
    float e1 = DPP_ADD(d1, 0xB1);
    float h = (l & 1) ? e1 : e0;
    h = DPP_ADD(h, 0x4E);           // quad_perm [2,3,0,1]  (xor 2)
    h = DPP_ADD(h, 0x124);          // row_ror:4
    h = DPP_ADD(h, 0x128);          // row_ror:8
    PERMLANE_SUM_1632(h)

    const float ut = u_s[t];
    if (l < ROWS_PER_WAVE) {
      // fast tanh: 1 - 2/(e^{2x}+1) via v_exp_f32 (2^x) + v_rcp_f32;
      // saturates correctly; ~1e-6 abs err (R7-proven).
      const float a = fmaf(winl, ut, h);
      float z;
      asm("v_exp_f32 %0, %1" : "=v"(z) : "v"(a * 2.885390082f));
      float r;
      asm("v_rcp_f32 %0, %1" : "=v"(r) : "v"(z + 1.0f));
      fresh[wv * ROWS_PER_WAVE + l] = fmaf(-2.0f, r, 1.0f);
    }
    __syncthreads();  // barrier 2: fresh[] complete

    // per-wave replica publish: wave wv (0..7) stores the WG's full 32-row
    // slice to replica wv (8 parallel 256B full-line stores).
    if (wv < nrepl && l < ROWS_PER_WG) {
      const unsigned long long pk =
          ((unsigned long long)__float_as_uint(fresh[l]) << 32) | (unsigned)t;
      __hip_atomic_store(
          pairs + (size_t)wv * REPL + (t & 1) * HIDDEN + g * ROWS_PER_WG + l,
          pk, __ATOMIC_RELAXED, __HIP_MEMORY_SCOPE_AGENT);
    }
    if (wv == 8 && t >= WASHOUT) {
      // distributed readout on a NON-publishing wave: this WG's 32-row
      // partial of x_t . w_out, all-VALU reduce (lanes >=32 contribute 0).
      float part = (l < 32) ? fresh[l] * wol : 0.f;
      part = DPP_ADD(part, 0xB1);
      part = DPP_ADD(part, 0x4E);
      part = DPP_ADD(part, 0x124);
      part = DPP_ADD(part, 0x128);
      PERMLANE_SUM_1632(part)
      if (l == 0) atomicAdd(&out[t - WASHOUT], part);
    }
  }
}

extern "C" void kernel_launch(void* const* d_in, const int* in_sizes, int n_in,
                              void* d_out, int out_size, void* d_ws, size_t ws_size,
                              hipStream_t stream) {
  const float* u     = (const float*)d_in[0];
  const float* w_in  = (const float*)d_in[1];
  const float* w_res = (const float*)d_in[2];
  const float* w_out = (const float*)d_in[3];
  float* out = (float*)d_out;
  unsigned long long* pairs = (unsigned long long*)d_ws;

  // replicas need NREPL * 32 KB of ws; fall back to a single mailbox
  const int nrepl =
      (ws_size >= (size_t)NREPL * REPL * sizeof(unsigned long long)) ? NREPL : 1;

  // out accumulates atomicAdd partials -> must start at zero every call
  hipMemsetAsync(out, 0, (size_t)out_size * sizeof(float), stream);
  esn_main<<<NWG, NTHR, 0, stream>>>(u, w_in, w_res, w_out, out, pairs, nrepl);
}